// Round 5
// baseline (2422.574 us; speedup 1.0000x reference)
//
#include <hip/hip_runtime.h>
#include <hip/hip_bf16.h>
#include <math.h>

typedef __bf16 bf16;
typedef __bf16 bf16x8 __attribute__((ext_vector_type(8)));
typedef float  f32x4  __attribute__((ext_vector_type(4)));

#define DEV __device__ __forceinline__

DEV f32x4 mfma16(bf16x8 a, bf16x8 b, f32x4 c) {
    return __builtin_amdgcn_mfma_f32_16x16x32_bf16(a, b, c, 0, 0, 0);
}

// ---------------------------------------------------------------------------
// Wide GEMM: C[M x N] = A[M x K] @ Bt[N x K]^T (+fp32 bias), 128x128, BK=32.
// Chunk-XOR swizzle (slot = c ^ ((row>>1)&3)): R4 measured SQ_LDS_BANK_CONFLICT
// 2.1e6 -> 0. Prefetch after 2nd barrier overlaps global loads with MFMAs.
// MODE 0: Cb = acc + bias (bf16 out). MODE 1: Cb = gelu(acc + bias).
// ---------------------------------------------------------------------------
template <int MODE>
__global__ __launch_bounds__(256, 2) void gemm_k(
    const bf16* __restrict__ A, const bf16* __restrict__ Bt,
    const float* __restrict__ bias, bf16* __restrict__ Cb,
    int K, int ldC)
{
    __shared__ bf16 As[128 * 32];
    __shared__ bf16 Bs[128 * 32];
    const int tid  = threadIdx.x;
    const int lane = tid & 63;
    const int w    = tid >> 6;
    const int wm   = w & 1, wn = w >> 1;
    const long tm  = (long)blockIdx.y * 128;
    const long tn  = (long)blockIdx.x * 128;

    f32x4 acc[4][4] = {};

    const int p0 = tid, p1 = tid + 256;
    const int r0 = p0 >> 2, c0 = (p0 & 3) * 8;
    const int r1 = p1 >> 2, c1 = (p1 & 3) * 8;
    const int s0 = r0 * 32 + (((p0 & 3) ^ ((r0 >> 1) & 3)) * 8);
    const int s1 = r1 * 32 + (((p1 & 3) ^ ((r1 >> 1) & 3)) * 8);
    const bf16* A0 = A + (tm + r0) * K + c0;
    const bf16* A1 = A + (tm + r1) * K + c1;
    const bf16* B0 = Bt + (tn + r0) * K + c0;
    const bf16* B1 = Bt + (tn + r1) * K + c1;

    int am[4], bn[4];
#pragma unroll
    for (int i = 0; i < 4; ++i) {
        int ra = wm * 64 + i * 16 + (lane & 15);
        am[i]  = ra * 32 + (((lane >> 4) ^ ((ra >> 1) & 3)) * 8);
        int rb = wn * 64 + i * 16 + (lane & 15);
        bn[i]  = rb * 32 + (((lane >> 4) ^ ((rb >> 1) & 3)) * 8);
    }

    uint4 va0 = *(const uint4*)A0;
    uint4 va1 = *(const uint4*)A1;
    uint4 vb0 = *(const uint4*)B0;
    uint4 vb1 = *(const uint4*)B1;

    for (int k0 = 0; k0 < K; k0 += 32) {
        __syncthreads();
        *(uint4*)&As[s0] = va0;
        *(uint4*)&As[s1] = va1;
        *(uint4*)&Bs[s0] = vb0;
        *(uint4*)&Bs[s1] = vb1;
        __syncthreads();
        if (k0 + 32 < K) {
            va0 = *(const uint4*)(A0 + k0 + 32);
            va1 = *(const uint4*)(A1 + k0 + 32);
            vb0 = *(const uint4*)(B0 + k0 + 32);
            vb1 = *(const uint4*)(B1 + k0 + 32);
        }
        bf16x8 a[4], b[4];
#pragma unroll
        for (int i = 0; i < 4; ++i) a[i] = *(const bf16x8*)&As[am[i]];
#pragma unroll
        for (int i = 0; i < 4; ++i) b[i] = *(const bf16x8*)&Bs[bn[i]];
#pragma unroll
        for (int mi = 0; mi < 4; ++mi)
#pragma unroll
            for (int ni = 0; ni < 4; ++ni)
                acc[mi][ni] = mfma16(a[mi], b[ni], acc[mi][ni]);
    }

#pragma unroll
    for (int mi = 0; mi < 4; ++mi) {
        const long rbase = tm + wm * 64 + mi * 16 + ((lane >> 4) << 2);
#pragma unroll
        for (int ni = 0; ni < 4; ++ni) {
            const long col = tn + wn * 64 + ni * 16 + (lane & 15);
            const float bv = bias[col];
#pragma unroll
            for (int r = 0; r < 4; ++r) {
                float v = acc[mi][ni][r] + bv;
                if constexpr (MODE == 1)
                    v = 0.5f * v * (1.0f + erff(v * 0.70710678118654752f));
                Cb[(rbase + r) * (long)ldC + col] = (bf16)v;
            }
        }
    }
}

// ---------------------------------------------------------------------------
// Skinny-N GEMM for proj/FFN2: 128M x 64N tile, BK=64, direct fp32 residual
// accumulate (no atomics -- R4 post-mortem: split-K atomics cost 4x write
// traffic and +15us). Grid 8x64 = 512 blocks = 2/CU. Swizzle: rows are 8
// chunks wide; slot chunk' = c ^ (row&7) -> frag reads 2-way max (free).
// ---------------------------------------------------------------------------
__global__ __launch_bounds__(256, 2) void gemm_sk(
    const bf16* __restrict__ A, const bf16* __restrict__ Bt,
    const float* __restrict__ bias, float* __restrict__ Cf,
    int K, int ldC)
{
    __shared__ bf16 As[128 * 64];
    __shared__ bf16 Bs[64 * 64];
    const int tid  = threadIdx.x;
    const int lane = tid & 63;
    const int w    = tid >> 6;
    const int wm   = w & 1, wn = w >> 1;   // wave: 64 rows x 32 cols
    const long tm  = (long)blockIdx.y * 128;
    const long tn  = (long)blockIdx.x * 64;

    f32x4 acc[4][2] = {};

    // A staging: 1024 positions (row = p>>3, chunk = p&7), 4 per thread
    int sa[4]; const bf16* ga[4];
#pragma unroll
    for (int i = 0; i < 4; ++i) {
        int p = i * 256 + tid, row = p >> 3, ch = p & 7;
        sa[i] = row * 64 + ((ch ^ (row & 7)) * 8);
        ga[i] = A + (tm + row) * K + ch * 8;
    }
    // B staging: 512 positions, 2 per thread
    int sb[2]; const bf16* gb[2];
#pragma unroll
    for (int i = 0; i < 2; ++i) {
        int p = i * 256 + tid, row = p >> 3, ch = p & 7;
        sb[i] = row * 64 + ((ch ^ (row & 7)) * 8);
        gb[i] = Bt + (tn + row) * K + ch * 8;
    }

    // fragment offsets: [ks][mi] for A, [ks][ni] for B
    int am[2][4], bn[2][2];
#pragma unroll
    for (int ks = 0; ks < 2; ++ks) {
#pragma unroll
        for (int mi = 0; mi < 4; ++mi) {
            int ra = wm * 64 + mi * 16 + (lane & 15);
            am[ks][mi] = ra * 64 + (((ks * 4 + (lane >> 4)) ^ (ra & 7)) * 8);
        }
#pragma unroll
        for (int ni = 0; ni < 2; ++ni) {
            int rb = wn * 32 + ni * 16 + (lane & 15);
            bn[ks][ni] = rb * 64 + (((ks * 4 + (lane >> 4)) ^ (rb & 7)) * 8);
        }
    }

    uint4 va[4], vb[2];
#pragma unroll
    for (int i = 0; i < 4; ++i) va[i] = *(const uint4*)ga[i];
#pragma unroll
    for (int i = 0; i < 2; ++i) vb[i] = *(const uint4*)gb[i];

    for (int k0 = 0; k0 < K; k0 += 64) {
        __syncthreads();
#pragma unroll
        for (int i = 0; i < 4; ++i) *(uint4*)&As[sa[i]] = va[i];
#pragma unroll
        for (int i = 0; i < 2; ++i) *(uint4*)&Bs[sb[i]] = vb[i];
        __syncthreads();
        if (k0 + 64 < K) {
#pragma unroll
            for (int i = 0; i < 4; ++i) va[i] = *(const uint4*)(ga[i] + k0 + 64);
#pragma unroll
            for (int i = 0; i < 2; ++i) vb[i] = *(const uint4*)(gb[i] + k0 + 64);
        }
#pragma unroll
        for (int ks = 0; ks < 2; ++ks) {
            bf16x8 a[4], b[2];
#pragma unroll
            for (int mi = 0; mi < 4; ++mi) a[mi] = *(const bf16x8*)&As[am[ks][mi]];
#pragma unroll
            for (int ni = 0; ni < 2; ++ni) b[ni] = *(const bf16x8*)&Bs[bn[ks][ni]];
#pragma unroll
            for (int mi = 0; mi < 4; ++mi)
#pragma unroll
                for (int ni = 0; ni < 2; ++ni)
                    acc[mi][ni] = mfma16(a[mi], b[ni], acc[mi][ni]);
        }
    }

#pragma unroll
    for (int mi = 0; mi < 4; ++mi) {
        const long rbase = tm + wm * 64 + mi * 16 + ((lane >> 4) << 2);
#pragma unroll
        for (int ni = 0; ni < 2; ++ni) {
            const long col = tn + wn * 32 + ni * 16 + (lane & 15);
            const float bv = bias[col];
#pragma unroll
            for (int r = 0; r < 4; ++r) {
                const long idx = (rbase + r) * (long)ldC + col;
                Cf[idx] += acc[mi][ni][r] + bv;
            }
        }
    }
}

// ---------------------------------------------------------------------------
// Attention: one block per (b, h, 64-row q tile). 4 waves; wave w handles
// 16 q rows. K staged [256][72] (pad 8, b128-clean), P reuses K region
// [w][16][264], V^T staged in two 32-d halves [32][264]. Bias is fp32.
// ---------------------------------------------------------------------------
__global__ __launch_bounds__(256, 2) void attn_k(
    const bf16* __restrict__ qkv, const float* __restrict__ bias,
    bf16* __restrict__ ctx)
{
    __shared__ bf16 smem[256 * 72 + 32 * 264];
    bf16* Ks = smem;
    bf16* Vt = smem + 256 * 72;

    const int tid = threadIdx.x, lane = tid & 63, w = tid >> 6;
    const int qt = blockIdx.x & 3;
    const int h  = (blockIdx.x >> 2) & 7;
    const int b  = blockIdx.x >> 5;
    const long qkv_base = (long)b * 256 * 1536;

#pragma unroll
    for (int i = 0; i < 8; ++i) {
        int p = i * 256 + tid;
        int n = p >> 3, kk = (p & 7) * 8;
        uint4 v = *(const uint4*)(qkv + qkv_base + (long)n * 1536 + 512 + h * 64 + kk);
        *(uint4*)&Ks[n * 72 + kk] = v;
    }
    {
        int d = tid & 31, nb = tid >> 5;
#pragma unroll 4
        for (int i = 0; i < 32; ++i) {
            int n = nb + i * 8;
            Vt[d * 264 + n] = qkv[qkv_base + (long)n * 1536 + 1024 + h * 64 + d];
        }
    }

    const int qr0 = qt * 64 + w * 16;
    bf16x8 aq0, aq1;
    {
        const bf16* g = qkv + qkv_base + (long)(qr0 + (lane & 15)) * 1536 + h * 64 + ((lane >> 4) * 8);
        aq0 = *(const bf16x8*)g;
        aq1 = *(const bf16x8*)(g + 32);
    }
    __syncthreads();

    f32x4 s[16];
    const float* bb = bias + (((long)(b * 8 + h)) * 256 + qr0) * 256;
#pragma unroll
    for (int ct = 0; ct < 16; ++ct) {
        const int col = ct * 16 + (lane & 15);
        f32x4 c;
#pragma unroll
        for (int r = 0; r < 4; ++r)
            c[r] = bb[(long)((lane >> 4) * 4 + r) * 256 + col];
        bf16x8 k0 = *(const bf16x8*)&Ks[(ct * 16 + (lane & 15)) * 72 + ((lane >> 4) * 8)];
        bf16x8 k1 = *(const bf16x8*)&Ks[(ct * 16 + (lane & 15)) * 72 + 32 + ((lane >> 4) * 8)];
        c = mfma16(aq0, k0, c);
        c = mfma16(aq1, k1, c);
        s[ct] = c;
    }

    float m[4] = {-1e30f, -1e30f, -1e30f, -1e30f};
#pragma unroll
    for (int ct = 0; ct < 16; ++ct)
#pragma unroll
        for (int r = 0; r < 4; ++r) m[r] = fmaxf(m[r], s[ct][r]);
#pragma unroll
    for (int r = 0; r < 4; ++r)
#pragma unroll
        for (int off = 1; off < 16; off <<= 1)
            m[r] = fmaxf(m[r], __shfl_xor(m[r], off));
    float l[4] = {0.f, 0.f, 0.f, 0.f};
#pragma unroll
    for (int ct = 0; ct < 16; ++ct)
#pragma unroll
        for (int r = 0; r < 4; ++r) {
            float p = __expf(s[ct][r] - m[r]);
            s[ct][r] = p;
            l[r] += p;
        }
#pragma unroll
    for (int r = 0; r < 4; ++r) {
#pragma unroll
        for (int off = 1; off < 16; off <<= 1) l[r] += __shfl_xor(l[r], off);
        l[r] = 1.0f / l[r];
    }

    __syncthreads();
    bf16* P = Ks + w * (16 * 264);
#pragma unroll
    for (int ct = 0; ct < 16; ++ct)
#pragma unroll
        for (int r = 0; r < 4; ++r)
            P[(long)((lane >> 4) * 4 + r) * 264 + ct * 16 + (lane & 15)] = (bf16)s[ct][r];

    bf16x8 ap[8];
#pragma unroll
    for (int nk = 0; nk < 8; ++nk)
        ap[nk] = *(const bf16x8*)&P[(lane & 15) * 264 + nk * 32 + (lane >> 4) * 8];

    f32x4 o[4];
#pragma unroll
    for (int dt = 0; dt < 2; ++dt) {
        f32x4 c = {};
#pragma unroll
        for (int nk = 0; nk < 8; ++nk) {
            bf16x8 bv = *(const bf16x8*)&Vt[(dt * 16 + (lane & 15)) * 264 + nk * 32 + (lane >> 4) * 8];
            c = mfma16(ap[nk], bv, c);
        }
        o[dt] = c;
    }

    __syncthreads();
    {
        int d = tid & 31, nb = tid >> 5;
#pragma unroll 4
        for (int i = 0; i < 32; ++i) {
            int n = nb + i * 8;
            Vt[d * 264 + n] = qkv[qkv_base + (long)n * 1536 + 1024 + h * 64 + 32 + d];
        }
    }
    __syncthreads();
#pragma unroll
    for (int dt = 0; dt < 2; ++dt) {
        f32x4 c = {};
#pragma unroll
        for (int nk = 0; nk < 8; ++nk) {
            bf16x8 bv = *(const bf16x8*)&Vt[(dt * 16 + (lane & 15)) * 264 + nk * 32 + (lane >> 4) * 8];
            c = mfma16(ap[nk], bv, c);
        }
        o[2 + dt] = c;
    }

#pragma unroll
    for (int dt = 0; dt < 4; ++dt) {
        const int col = h * 64 + dt * 16 + (lane & 15);
#pragma unroll
        for (int r = 0; r < 4; ++r) {
            const long row = (long)b * 256 + qr0 + (lane >> 4) * 4 + r;
            ctx[row * 512 + col] = (bf16)(o[dt][r] * l[r]);
        }
    }
}

// ---------------------------------------------------------------------------
// LayerNorm: fp32 input rows of 512, fp32 scale/bias, bf16 out. 1 wave/row.
// ---------------------------------------------------------------------------
__global__ __launch_bounds__(256) void ln_k(
    const float* __restrict__ x, const float* __restrict__ sc,
    const float* __restrict__ bi, bf16* __restrict__ y)
{
    const int lane = threadIdx.x & 63;
    const long row = (long)blockIdx.x * 4 + (threadIdx.x >> 6);
    const float* xr = x + row * 512;
    float v[8];
    *(float4*)&v[0] = ((const float4*)xr)[lane * 2];
    *(float4*)&v[4] = ((const float4*)xr)[lane * 2 + 1];
    float sum = 0.f;
#pragma unroll
    for (int j = 0; j < 8; ++j) sum += v[j];
#pragma unroll
    for (int off = 1; off < 64; off <<= 1) sum += __shfl_xor(sum, off);
    const float mu = sum * (1.0f / 512.0f);
    float sq = 0.f;
#pragma unroll
    for (int j = 0; j < 8; ++j) { float d = v[j] - mu; sq += d * d; }
#pragma unroll
    for (int off = 1; off < 64; off <<= 1) sq += __shfl_xor(sq, off);
    const float rs = rsqrtf(sq * (1.0f / 512.0f) + 1e-5f);
    bf16* yr = y + row * 512;
#pragma unroll
    for (int j = 0; j < 8; ++j) {
        int c = lane * 8 + j;
        yr[c] = (bf16)((v[j] - mu) * rs * sc[c] + bi[c]);
    }
}

// ---------------------------------------------------------------------------
// One-shot weight transpose fp32 -> bf16 [N][K] layout (q-scale folded).
// ---------------------------------------------------------------------------
__global__ __launch_bounds__(256) void transpose_k(
    const float* __restrict__ wq, const float* __restrict__ wk,
    const float* __restrict__ wv, const float* __restrict__ wo,
    const float* __restrict__ w1, const float* __restrict__ w2,
    bf16* __restrict__ qkvT, bf16* __restrict__ woT,
    bf16* __restrict__ w1T, bf16* __restrict__ w2T)
{
    __shared__ float tile[32][33];
    const int tid = threadIdx.x, tx = tid & 31, ty = tid >> 5;
    const int l = blockIdx.x / 3072;
    const int r = blockIdx.x % 3072;

    const float* In = nullptr;
    bf16* Out = nullptr;
    int Nd, tk, tn, rowOff = 0, ldO;
    float scale = 1.0f;
    if (r < 1024) {
        const int which = r >> 8, t = r & 255;
        tn = t >> 4; tk = t & 15; Nd = 512; ldO = 512;
        const long woff = (long)l * 512 * 512;
        if (which == 0)      { In = wq + woff; Out = qkvT + (long)l * 1536 * 512; rowOff = 0;    scale = 0.125f; }
        else if (which == 1) { In = wk + woff; Out = qkvT + (long)l * 1536 * 512; rowOff = 512;  }
        else if (which == 2) { In = wv + woff; Out = qkvT + (long)l * 1536 * 512; rowOff = 1024; }
        else                 { In = wo + woff; Out = woT + woff; }
    } else if (r < 2048) {
        const int t = r - 1024;
        tn = t >> 4; tk = t & 15; Nd = 2048; ldO = 512;
        In = w1 + (long)l * 512 * 2048; Out = w1T + (long)l * 2048 * 512;
    } else {
        const int t = r - 2048;
        tn = t & 15; tk = t >> 4; Nd = 512; ldO = 2048;
        In = w2 + (long)l * 2048 * 512; Out = w2T + (long)l * 512 * 2048;
    }
    const int gk = tk * 32, gn = tn * 32;
#pragma unroll
    for (int j = 0; j < 4; ++j) {
        int rr = ty + j * 8;
        tile[rr][tx] = In[(long)(gk + rr) * Nd + gn + tx] * scale;
    }
    __syncthreads();
#pragma unroll
    for (int j = 0; j < 4; ++j) {
        int rr = ty + j * 8;
        Out[(long)(rowOff + gn + rr) * ldO + gk + tx] = (bf16)tile[tx][rr];
    }
}

__global__ void biasq_k(const float* __restrict__ bq, const float* __restrict__ bk,
                        const float* __restrict__ bv, float* __restrict__ bqkv)
{
    int i = blockIdx.x * 256 + threadIdx.x;
    if (i >= 8 * 1536) return;
    int l = i / 1536, j = i % 1536;
    float v;
    if (j < 512)       v = bq[l * 512 + j] * 0.125f;
    else if (j < 1024) v = bk[l * 512 + j - 512];
    else               v = bv[l * 512 + j - 1024];
    bqkv[i] = v;
}

// ---------------------------------------------------------------------------
extern "C" void kernel_launch(void* const* d_in, const int* in_sizes, int n_in,
                              void* d_out, int out_size, void* d_ws, size_t ws_size,
                              hipStream_t stream)
{
    (void)in_sizes; (void)n_in; (void)out_size; (void)ws_size;
    const float* x    = (const float*)d_in[0];
    const float* ab   = (const float*)d_in[1];
    const float* ln1s = (const float*)d_in[2];
    const float* ln1b = (const float*)d_in[3];
    const float* wq   = (const float*)d_in[4];
    const float* bq   = (const float*)d_in[5];
    const float* wk   = (const float*)d_in[6];
    const float* bk   = (const float*)d_in[7];
    const float* wv   = (const float*)d_in[8];
    const float* bv   = (const float*)d_in[9];
    const float* wo   = (const float*)d_in[10];
    const float* bo   = (const float*)d_in[11];
    const float* ln2s = (const float*)d_in[12];
    const float* ln2b = (const float*)d_in[13];
    const float* w1   = (const float*)d_in[14];
    const float* b1   = (const float*)d_in[15];
    const float* w2   = (const float*)d_in[16];
    const float* b2   = (const float*)d_in[17];

    char* ws = (char*)d_ws;
    float* xf   = (float*)ws;
    bf16* y     = (bf16*)(ws + 16777216);
    bf16* ctx   = y;
    bf16* qkv   = (bf16*)(ws + 16777216 + 8388608);
    bf16* ffn   = qkv;
    bf16* wqkvT = (bf16*)(ws + 16777216 + 8388608 + 33554432);
    bf16* woT   = wqkvT + (long)8 * 1536 * 512;
    bf16* w1T   = woT + (long)8 * 512 * 512;
    bf16* w2T   = w1T + (long)8 * 2048 * 512;
    float* bqkv = (float*)(w2T + (long)8 * 512 * 2048);

    hipMemcpyAsync(xf, x, (size_t)8192 * 512 * 4, hipMemcpyDeviceToDevice, stream);
    transpose_k<<<24576, 256, 0, stream>>>(wq, wk, wv, wo, w1, w2, wqkvT, woT, w1T, w2T);
    biasq_k<<<48, 256, 0, stream>>>(bq, bk, bv, bqkv);

    for (int l = 0; l < 8; ++l) {
        ln_k<<<2048, 256, 0, stream>>>(xf, ln1s + l * 512, ln1b + l * 512, y);
        gemm_k<0><<<dim3(12, 64), 256, 0, stream>>>(
            y, wqkvT + (long)l * 1536 * 512, bqkv + l * 1536, qkv, 512, 1536);
        attn_k<<<1024, 256, 0, stream>>>(qkv, ab, ctx);
        gemm_sk<<<dim3(8, 64), 256, 0, stream>>>(
            ctx, woT + (long)l * 512 * 512, bo + l * 512, xf, 512, 512);
        ln_k<<<2048, 256, 0, stream>>>(xf, ln2s + l * 512, ln2b + l * 512, y);
        gemm_k<1><<<dim3(16, 64), 256, 0, stream>>>(
            y, w1T + (long)l * 2048 * 512, b1 + l * 2048, ffn, 512, 2048);
        gemm_sk<<<dim3(8, 64), 256, 0, stream>>>(
            ffn, w2T + (long)l * 512 * 2048, b2 + l * 512, xf, 2048, 512);
    }
    hipMemcpyAsync(d_out, xf, (size_t)8192 * 512 * 4, hipMemcpyDeviceToDevice, stream);
}

// Round 6
// 1369.198 us; speedup vs baseline: 1.7693x; 1.7693x over previous
//
#include <hip/hip_runtime.h>
#include <hip/hip_bf16.h>
#include <math.h>

typedef __bf16 bf16;
typedef __bf16 bf16x8 __attribute__((ext_vector_type(8)));
typedef float  f32x4  __attribute__((ext_vector_type(4)));

#define DEV __device__ __forceinline__

DEV f32x4 mfma16(bf16x8 a, bf16x8 b, f32x4 c) {
    return __builtin_amdgcn_mfma_f32_16x16x32_bf16(a, b, c, 0, 0, 0);
}

// ---------------------------------------------------------------------------
// Wide GEMM: C[M x N] = A[M x K] @ Bt[N x K]^T (+fp32 bias), 128x128, BK=32.
// Chunk-XOR swizzle (conflicts 2.1e6 -> 0, R4-measured) + prefetch.
// MODE 0: Cb = acc + bias. MODE 1: Cb = gelu(acc + bias).
// ---------------------------------------------------------------------------
template <int MODE>
__global__ __launch_bounds__(256, 2) void gemm_k(
    const bf16* __restrict__ A, const bf16* __restrict__ Bt,
    const float* __restrict__ bias, bf16* __restrict__ Cb,
    int K, int ldC)
{
    __shared__ bf16 As[128 * 32];
    __shared__ bf16 Bs[128 * 32];
    const int tid  = threadIdx.x;
    const int lane = tid & 63;
    const int w    = tid >> 6;
    const int wm   = w & 1, wn = w >> 1;
    const long tm  = (long)blockIdx.y * 128;
    const long tn  = (long)blockIdx.x * 128;

    f32x4 acc[4][4] = {};

    const int p0 = tid, p1 = tid + 256;
    const int r0 = p0 >> 2, c0 = (p0 & 3) * 8;
    const int r1 = p1 >> 2, c1 = (p1 & 3) * 8;
    const int s0 = r0 * 32 + (((p0 & 3) ^ ((r0 >> 1) & 3)) * 8);
    const int s1 = r1 * 32 + (((p1 & 3) ^ ((r1 >> 1) & 3)) * 8);
    const bf16* A0 = A + (tm + r0) * K + c0;
    const bf16* A1 = A + (tm + r1) * K + c1;
    const bf16* B0 = Bt + (tn + r0) * K + c0;
    const bf16* B1 = Bt + (tn + r1) * K + c1;

    int am[4], bn[4];
#pragma unroll
    for (int i = 0; i < 4; ++i) {
        int ra = wm * 64 + i * 16 + (lane & 15);
        am[i]  = ra * 32 + (((lane >> 4) ^ ((ra >> 1) & 3)) * 8);
        int rb = wn * 64 + i * 16 + (lane & 15);
        bn[i]  = rb * 32 + (((lane >> 4) ^ ((rb >> 1) & 3)) * 8);
    }

    uint4 va0 = *(const uint4*)A0;
    uint4 va1 = *(const uint4*)A1;
    uint4 vb0 = *(const uint4*)B0;
    uint4 vb1 = *(const uint4*)B1;

    for (int k0 = 0; k0 < K; k0 += 32) {
        __syncthreads();
        *(uint4*)&As[s0] = va0;
        *(uint4*)&As[s1] = va1;
        *(uint4*)&Bs[s0] = vb0;
        *(uint4*)&Bs[s1] = vb1;
        __syncthreads();
        if (k0 + 32 < K) {
            va0 = *(const uint4*)(A0 + k0 + 32);
            va1 = *(const uint4*)(A1 + k0 + 32);
            vb0 = *(const uint4*)(B0 + k0 + 32);
            vb1 = *(const uint4*)(B1 + k0 + 32);
        }
        bf16x8 a[4], b[4];
#pragma unroll
        for (int i = 0; i < 4; ++i) a[i] = *(const bf16x8*)&As[am[i]];
#pragma unroll
        for (int i = 0; i < 4; ++i) b[i] = *(const bf16x8*)&Bs[bn[i]];
#pragma unroll
        for (int mi = 0; mi < 4; ++mi)
#pragma unroll
            for (int ni = 0; ni < 4; ++ni)
                acc[mi][ni] = mfma16(a[mi], b[ni], acc[mi][ni]);
    }

#pragma unroll
    for (int mi = 0; mi < 4; ++mi) {
        const long rbase = tm + wm * 64 + mi * 16 + ((lane >> 4) << 2);
#pragma unroll
        for (int ni = 0; ni < 4; ++ni) {
            const long col = tn + wn * 64 + ni * 16 + (lane & 15);
            const float bv = bias[col];
#pragma unroll
            for (int r = 0; r < 4; ++r) {
                float v = acc[mi][ni][r] + bv;
                if constexpr (MODE == 1)
                    v = 0.5f * v * (1.0f + erff(v * 0.70710678118654752f));
                Cb[(rbase + r) * (long)ldC + col] = (bf16)v;
            }
        }
    }
}

// ---------------------------------------------------------------------------
// Split-K delta GEMM for proj/FFN2 (N=512): 128x128 tile, BK=32, z = K-slice.
// Writes bf16 delta slice (dense stores -- R4/R5 post-mortem: atomics = 4x
// writes, fp32 RMW = 15x writes; both banned). Residual-add happens in the
// fused LN that consumes the two slices. Grid 4x64x2 = 512 blocks = 2/CU.
// ---------------------------------------------------------------------------
__global__ __launch_bounds__(256, 2) void gemm_dk(
    const bf16* __restrict__ A, const bf16* __restrict__ Bt,
    bf16* __restrict__ D, int K, int Ks)
{
    __shared__ bf16 As[128 * 32];
    __shared__ bf16 Bs[128 * 32];
    const int tid  = threadIdx.x;
    const int lane = tid & 63;
    const int w    = tid >> 6;
    const int wm   = w & 1, wn = w >> 1;
    const long tm  = (long)blockIdx.y * 128;
    const long tn  = (long)blockIdx.x * 128;
    const int kbase = blockIdx.z * Ks;

    f32x4 acc[4][4] = {};

    const int p0 = tid, p1 = tid + 256;
    const int r0 = p0 >> 2, c0 = (p0 & 3) * 8;
    const int r1 = p1 >> 2, c1 = (p1 & 3) * 8;
    const int s0 = r0 * 32 + (((p0 & 3) ^ ((r0 >> 1) & 3)) * 8);
    const int s1 = r1 * 32 + (((p1 & 3) ^ ((r1 >> 1) & 3)) * 8);
    const bf16* A0 = A + (tm + r0) * K + kbase + c0;
    const bf16* A1 = A + (tm + r1) * K + kbase + c1;
    const bf16* B0 = Bt + (tn + r0) * K + kbase + c0;
    const bf16* B1 = Bt + (tn + r1) * K + kbase + c1;

    int am[4], bn[4];
#pragma unroll
    for (int i = 0; i < 4; ++i) {
        int ra = wm * 64 + i * 16 + (lane & 15);
        am[i]  = ra * 32 + (((lane >> 4) ^ ((ra >> 1) & 3)) * 8);
        int rb = wn * 64 + i * 16 + (lane & 15);
        bn[i]  = rb * 32 + (((lane >> 4) ^ ((rb >> 1) & 3)) * 8);
    }

    uint4 va0 = *(const uint4*)A0;
    uint4 va1 = *(const uint4*)A1;
    uint4 vb0 = *(const uint4*)B0;
    uint4 vb1 = *(const uint4*)B1;

    for (int k0 = 0; k0 < Ks; k0 += 32) {
        __syncthreads();
        *(uint4*)&As[s0] = va0;
        *(uint4*)&As[s1] = va1;
        *(uint4*)&Bs[s0] = vb0;
        *(uint4*)&Bs[s1] = vb1;
        __syncthreads();
        if (k0 + 32 < Ks) {
            va0 = *(const uint4*)(A0 + k0 + 32);
            va1 = *(const uint4*)(A1 + k0 + 32);
            vb0 = *(const uint4*)(B0 + k0 + 32);
            vb1 = *(const uint4*)(B1 + k0 + 32);
        }
        bf16x8 a[4], b[4];
#pragma unroll
        for (int i = 0; i < 4; ++i) a[i] = *(const bf16x8*)&As[am[i]];
#pragma unroll
        for (int i = 0; i < 4; ++i) b[i] = *(const bf16x8*)&Bs[bn[i]];
#pragma unroll
        for (int mi = 0; mi < 4; ++mi)
#pragma unroll
            for (int ni = 0; ni < 4; ++ni)
                acc[mi][ni] = mfma16(a[mi], b[ni], acc[mi][ni]);
    }

    bf16* Dp = D + (long)blockIdx.z * 8192 * 512;
#pragma unroll
    for (int mi = 0; mi < 4; ++mi) {
        const long rbase = tm + wm * 64 + mi * 16 + ((lane >> 4) << 2);
#pragma unroll
        for (int ni = 0; ni < 4; ++ni) {
            const long col = tn + wn * 64 + ni * 16 + (lane & 15);
#pragma unroll
            for (int r = 0; r < 4; ++r)
                Dp[(rbase + r) * 512 + col] = (bf16)acc[mi][ni][r];
        }
    }
}

// ---------------------------------------------------------------------------
// Attention: one block per (b, h, 64-row q tile). Unchanged from R3 (passing).
// ---------------------------------------------------------------------------
__global__ __launch_bounds__(256, 2) void attn_k(
    const bf16* __restrict__ qkv, const float* __restrict__ bias,
    bf16* __restrict__ ctx)
{
    __shared__ bf16 smem[256 * 72 + 32 * 264];
    bf16* Ks = smem;
    bf16* Vt = smem + 256 * 72;

    const int tid = threadIdx.x, lane = tid & 63, w = tid >> 6;
    const int qt = blockIdx.x & 3;
    const int h  = (blockIdx.x >> 2) & 7;
    const int b  = blockIdx.x >> 5;
    const long qkv_base = (long)b * 256 * 1536;

#pragma unroll
    for (int i = 0; i < 8; ++i) {
        int p = i * 256 + tid;
        int n = p >> 3, kk = (p & 7) * 8;
        uint4 v = *(const uint4*)(qkv + qkv_base + (long)n * 1536 + 512 + h * 64 + kk);
        *(uint4*)&Ks[n * 72 + kk] = v;
    }
    {
        int d = tid & 31, nb = tid >> 5;
#pragma unroll 4
        for (int i = 0; i < 32; ++i) {
            int n = nb + i * 8;
            Vt[d * 264 + n] = qkv[qkv_base + (long)n * 1536 + 1024 + h * 64 + d];
        }
    }

    const int qr0 = qt * 64 + w * 16;
    bf16x8 aq0, aq1;
    {
        const bf16* g = qkv + qkv_base + (long)(qr0 + (lane & 15)) * 1536 + h * 64 + ((lane >> 4) * 8);
        aq0 = *(const bf16x8*)g;
        aq1 = *(const bf16x8*)(g + 32);
    }
    __syncthreads();

    f32x4 s[16];
    const float* bb = bias + (((long)(b * 8 + h)) * 256 + qr0) * 256;
#pragma unroll
    for (int ct = 0; ct < 16; ++ct) {
        const int col = ct * 16 + (lane & 15);
        f32x4 c;
#pragma unroll
        for (int r = 0; r < 4; ++r)
            c[r] = bb[(long)((lane >> 4) * 4 + r) * 256 + col];
        bf16x8 k0 = *(const bf16x8*)&Ks[(ct * 16 + (lane & 15)) * 72 + ((lane >> 4) * 8)];
        bf16x8 k1 = *(const bf16x8*)&Ks[(ct * 16 + (lane & 15)) * 72 + 32 + ((lane >> 4) * 8)];
        c = mfma16(aq0, k0, c);
        c = mfma16(aq1, k1, c);
        s[ct] = c;
    }

    float m[4] = {-1e30f, -1e30f, -1e30f, -1e30f};
#pragma unroll
    for (int ct = 0; ct < 16; ++ct)
#pragma unroll
        for (int r = 0; r < 4; ++r) m[r] = fmaxf(m[r], s[ct][r]);
#pragma unroll
    for (int r = 0; r < 4; ++r)
#pragma unroll
        for (int off = 1; off < 16; off <<= 1)
            m[r] = fmaxf(m[r], __shfl_xor(m[r], off));
    float l[4] = {0.f, 0.f, 0.f, 0.f};
#pragma unroll
    for (int ct = 0; ct < 16; ++ct)
#pragma unroll
        for (int r = 0; r < 4; ++r) {
            float p = __expf(s[ct][r] - m[r]);
            s[ct][r] = p;
            l[r] += p;
        }
#pragma unroll
    for (int r = 0; r < 4; ++r) {
#pragma unroll
        for (int off = 1; off < 16; off <<= 1) l[r] += __shfl_xor(l[r], off);
        l[r] = 1.0f / l[r];
    }

    __syncthreads();
    bf16* P = Ks + w * (16 * 264);
#pragma unroll
    for (int ct = 0; ct < 16; ++ct)
#pragma unroll
        for (int r = 0; r < 4; ++r)
            P[(long)((lane >> 4) * 4 + r) * 264 + ct * 16 + (lane & 15)] = (bf16)s[ct][r];

    bf16x8 ap[8];
#pragma unroll
    for (int nk = 0; nk < 8; ++nk)
        ap[nk] = *(const bf16x8*)&P[(lane & 15) * 264 + nk * 32 + (lane >> 4) * 8];

    f32x4 o[4];
#pragma unroll
    for (int dt = 0; dt < 2; ++dt) {
        f32x4 c = {};
#pragma unroll
        for (int nk = 0; nk < 8; ++nk) {
            bf16x8 bv = *(const bf16x8*)&Vt[(dt * 16 + (lane & 15)) * 264 + nk * 32 + (lane >> 4) * 8];
            c = mfma16(ap[nk], bv, c);
        }
        o[dt] = c;
    }

    __syncthreads();
    {
        int d = tid & 31, nb = tid >> 5;
#pragma unroll 4
        for (int i = 0; i < 32; ++i) {
            int n = nb + i * 8;
            Vt[d * 264 + n] = qkv[qkv_base + (long)n * 1536 + 1024 + h * 64 + 32 + d];
        }
    }
    __syncthreads();
#pragma unroll
    for (int dt = 0; dt < 2; ++dt) {
        f32x4 c = {};
#pragma unroll
        for (int nk = 0; nk < 8; ++nk) {
            bf16x8 bv = *(const bf16x8*)&Vt[(dt * 16 + (lane & 15)) * 264 + nk * 32 + (lane >> 4) * 8];
            c = mfma16(ap[nk], bv, c);
        }
        o[2 + dt] = c;
    }

#pragma unroll
    for (int dt = 0; dt < 4; ++dt) {
        const int col = h * 64 + dt * 16 + (lane & 15);
#pragma unroll
        for (int r = 0; r < 4; ++r) {
            const long row = (long)b * 256 + qr0 + (lane >> 4) * 4 + r;
            ctx[row * 512 + col] = (bf16)(o[dt][r] * l[r]);
        }
    }
}

// ---------------------------------------------------------------------------
// Fused residual-add + LayerNorm. NS = number of bf16 delta slices (0 or 2).
// NS=2: xf_new = xf + d0 + d1 + rbias; write xf_new and y = LN(xf_new).
// NS=0: y = LN(xf) only. One wave per row of 512.
// ---------------------------------------------------------------------------
template <int NS>
__global__ __launch_bounds__(256) void ln_k(
    const float* __restrict__ x, float* __restrict__ xout,
    const bf16* __restrict__ d, const float* __restrict__ rbias,
    const float* __restrict__ sc, const float* __restrict__ bi,
    bf16* __restrict__ y)
{
    const int lane = threadIdx.x & 63;
    const long row = (long)blockIdx.x * 4 + (threadIdx.x >> 6);
    const float* xr = x + row * 512;
    float v[8];
    *(float4*)&v[0] = ((const float4*)xr)[lane * 2];
    *(float4*)&v[4] = ((const float4*)xr)[lane * 2 + 1];
    if constexpr (NS == 2) {
        bf16x8 d0 = *(const bf16x8*)&d[row * 512 + lane * 8];
        bf16x8 d1 = *(const bf16x8*)&d[(long)8192 * 512 + row * 512 + lane * 8];
        float b4[8];
        *(float4*)&b4[0] = ((const float4*)rbias)[lane * 2];
        *(float4*)&b4[4] = ((const float4*)rbias)[lane * 2 + 1];
#pragma unroll
        for (int j = 0; j < 8; ++j)
            v[j] += (float)d0[j] + (float)d1[j] + b4[j];
        float* xo = xout + row * 512;
        ((float4*)xo)[lane * 2]     = *(const float4*)&v[0];
        ((float4*)xo)[lane * 2 + 1] = *(const float4*)&v[4];
    }
    float sum = 0.f;
#pragma unroll
    for (int j = 0; j < 8; ++j) sum += v[j];
#pragma unroll
    for (int off = 1; off < 64; off <<= 1) sum += __shfl_xor(sum, off);
    const float mu = sum * (1.0f / 512.0f);
    float sq = 0.f;
#pragma unroll
    for (int j = 0; j < 8; ++j) { float dd = v[j] - mu; sq += dd * dd; }
#pragma unroll
    for (int off = 1; off < 64; off <<= 1) sq += __shfl_xor(sq, off);
    const float rs = rsqrtf(sq * (1.0f / 512.0f) + 1e-5f);
    bf16* yr = y + row * 512;
#pragma unroll
    for (int j = 0; j < 8; ++j) {
        int c = lane * 8 + j;
        yr[c] = (bf16)((v[j] - mu) * rs * sc[c] + bi[c]);
    }
}

// final: out = xf + d0 + d1 + rbias (fp32)
__global__ __launch_bounds__(256) void addout_k(
    const float* __restrict__ x, const bf16* __restrict__ d,
    const float* __restrict__ rbias, float* __restrict__ out)
{
    const int lane = threadIdx.x & 63;
    const long row = (long)blockIdx.x * 4 + (threadIdx.x >> 6);
    float v[8];
    *(float4*)&v[0] = ((const float4*)(x + row * 512))[lane * 2];
    *(float4*)&v[4] = ((const float4*)(x + row * 512))[lane * 2 + 1];
    bf16x8 d0 = *(const bf16x8*)&d[row * 512 + lane * 8];
    bf16x8 d1 = *(const bf16x8*)&d[(long)8192 * 512 + row * 512 + lane * 8];
    float b4[8];
    *(float4*)&b4[0] = ((const float4*)rbias)[lane * 2];
    *(float4*)&b4[4] = ((const float4*)rbias)[lane * 2 + 1];
#pragma unroll
    for (int j = 0; j < 8; ++j)
        v[j] += (float)d0[j] + (float)d1[j] + b4[j];
    float* o = out + row * 512;
    ((float4*)o)[lane * 2]     = *(const float4*)&v[0];
    ((float4*)o)[lane * 2 + 1] = *(const float4*)&v[4];
}

// ---------------------------------------------------------------------------
// One-shot weight transpose fp32 -> bf16 [N][K] layout (q-scale folded).
// ---------------------------------------------------------------------------
__global__ __launch_bounds__(256) void transpose_k(
    const float* __restrict__ wq, const float* __restrict__ wk,
    const float* __restrict__ wv, const float* __restrict__ wo,
    const float* __restrict__ w1, const float* __restrict__ w2,
    bf16* __restrict__ qkvT, bf16* __restrict__ woT,
    bf16* __restrict__ w1T, bf16* __restrict__ w2T)
{
    __shared__ float tile[32][33];
    const int tid = threadIdx.x, tx = tid & 31, ty = tid >> 5;
    const int l = blockIdx.x / 3072;
    const int r = blockIdx.x % 3072;

    const float* In = nullptr;
    bf16* Out = nullptr;
    int Nd, tk, tn, rowOff = 0, ldO;
    float scale = 1.0f;
    if (r < 1024) {
        const int which = r >> 8, t = r & 255;
        tn = t >> 4; tk = t & 15; Nd = 512; ldO = 512;
        const long woff = (long)l * 512 * 512;
        if (which == 0)      { In = wq + woff; Out = qkvT + (long)l * 1536 * 512; rowOff = 0;    scale = 0.125f; }
        else if (which == 1) { In = wk + woff; Out = qkvT + (long)l * 1536 * 512; rowOff = 512;  }
        else if (which == 2) { In = wv + woff; Out = qkvT + (long)l * 1536 * 512; rowOff = 1024; }
        else                 { In = wo + woff; Out = woT + woff; }
    } else if (r < 2048) {
        const int t = r - 1024;
        tn = t >> 4; tk = t & 15; Nd = 2048; ldO = 512;
        In = w1 + (long)l * 512 * 2048; Out = w1T + (long)l * 2048 * 512;
    } else {
        const int t = r - 2048;
        tn = t & 15; tk = t >> 4; Nd = 512; ldO = 2048;
        In = w2 + (long)l * 2048 * 512; Out = w2T + (long)l * 512 * 2048;
    }
    const int gk = tk * 32, gn = tn * 32;
#pragma unroll
    for (int j = 0; j < 4; ++j) {
        int rr = ty + j * 8;
        tile[rr][tx] = In[(long)(gk + rr) * Nd + gn + tx] * scale;
    }
    __syncthreads();
#pragma unroll
    for (int j = 0; j < 4; ++j) {
        int rr = ty + j * 8;
        Out[(long)(rowOff + gn + rr) * ldO + gk + tx] = (bf16)tile[tx][rr];
    }
}

__global__ void biasq_k(const float* __restrict__ bq, const float* __restrict__ bk,
                        const float* __restrict__ bv, float* __restrict__ bqkv)
{
    int i = blockIdx.x * 256 + threadIdx.x;
    if (i >= 8 * 1536) return;
    int l = i / 1536, j = i % 1536;
    float v;
    if (j < 512)       v = bq[l * 512 + j] * 0.125f;
    else if (j < 1024) v = bk[l * 512 + j - 512];
    else               v = bv[l * 512 + j - 1024];
    bqkv[i] = v;
}

// ---------------------------------------------------------------------------
extern "C" void kernel_launch(void* const* d_in, const int* in_sizes, int n_in,
                              void* d_out, int out_size, void* d_ws, size_t ws_size,
                              hipStream_t stream)
{
    (void)in_sizes; (void)n_in; (void)out_size; (void)ws_size;
    const float* x    = (const float*)d_in[0];
    const float* ab   = (const float*)d_in[1];
    const float* ln1s = (const float*)d_in[2];
    const float* ln1b = (const float*)d_in[3];
    const float* wq   = (const float*)d_in[4];
    const float* bq   = (const float*)d_in[5];
    const float* wk   = (const float*)d_in[6];
    const float* bk   = (const float*)d_in[7];
    const float* wv   = (const float*)d_in[8];
    const float* bv   = (const float*)d_in[9];
    const float* wo   = (const float*)d_in[10];
    const float* bo   = (const float*)d_in[11];
    const float* ln2s = (const float*)d_in[12];
    const float* ln2b = (const float*)d_in[13];
    const float* w1   = (const float*)d_in[14];
    const float* b1   = (const float*)d_in[15];
    const float* w2   = (const float*)d_in[16];
    const float* b2   = (const float*)d_in[17];

    char* ws = (char*)d_ws;
    // [0,16M) xf fp32 | [16M,24M) y/ctx bf16 | [24M,56M) qkv/ffn bf16
    // [56M,72M) delta bf16 [2][8192][512] | [72M,~120M) weights + bqkv
    float* xf   = (float*)ws;
    bf16* y     = (bf16*)(ws + 16777216);
    bf16* ctx   = y;
    bf16* qkv   = (bf16*)(ws + 16777216 + 8388608);
    bf16* ffn   = qkv;
    bf16* dbuf  = (bf16*)(ws + 16777216 + 8388608 + 33554432);
    bf16* wqkvT = dbuf + (long)2 * 8192 * 512;
    bf16* woT   = wqkvT + (long)8 * 1536 * 512;
    bf16* w1T   = woT + (long)8 * 512 * 512;
    bf16* w2T   = w1T + (long)8 * 2048 * 512;
    float* bqkv = (float*)(w2T + (long)8 * 512 * 2048);

    hipMemcpyAsync(xf, x, (size_t)8192 * 512 * 4, hipMemcpyDeviceToDevice, stream);
    transpose_k<<<24576, 256, 0, stream>>>(wq, wk, wv, wo, w1, w2, wqkvT, woT, w1T, w2T);
    biasq_k<<<48, 256, 0, stream>>>(bq, bk, bv, bqkv);

    for (int l = 0; l < 8; ++l) {
        if (l == 0)
            ln_k<0><<<2048, 256, 0, stream>>>(xf, nullptr, nullptr, nullptr,
                                              ln1s, ln1b, y);
        else
            ln_k<2><<<2048, 256, 0, stream>>>(xf, xf, dbuf, b2 + (l - 1) * 512,
                                              ln1s + l * 512, ln1b + l * 512, y);
        gemm_k<0><<<dim3(12, 64), 256, 0, stream>>>(
            y, wqkvT + (long)l * 1536 * 512, bqkv + l * 1536, qkv, 512, 1536);
        attn_k<<<1024, 256, 0, stream>>>(qkv, ab, ctx);
        gemm_dk<<<dim3(4, 64, 2), 256, 0, stream>>>(
            ctx, woT + (long)l * 512 * 512, dbuf, 512, 256);
        ln_k<2><<<2048, 256, 0, stream>>>(xf, xf, dbuf, bo + l * 512,
                                          ln2s + l * 512, ln2b + l * 512, y);
        gemm_k<1><<<dim3(16, 64), 256, 0, stream>>>(
            y, w1T + (long)l * 2048 * 512, b1 + l * 2048, ffn, 512, 2048);
        gemm_dk<<<dim3(4, 64, 2), 256, 0, stream>>>(
            ffn, w2T + (long)l * 512 * 2048, dbuf, 2048, 1024);
    }
    addout_k<<<2048, 256, 0, stream>>>(xf, dbuf, b2 + 7 * 512, (float*)d_out);
}